// Round 3
// baseline (1254.474 us; speedup 1.0000x reference)
//
#include <hip/hip_runtime.h>

// GCN 2-layer + linear head on MI355X.
// R2: killed write amplification. Old scatter: random 4B stores -> 64B line
// writebacks (WRITE_SIZE 86MB for 5MB payload, 106us). Now: counting-sort
// edges into 391 buckets of 256 nodes (dense-ish packed writes), aggregate
// per-bucket into a 64KB LDS accumulator (no CSR, no global atomics).

constexpr int TPB = 256;
constexpr int NB_SHIFT = 8;                 // 256 nodes per bucket
constexpr int BUCK_NODES = 1 << NB_SHIFT;
constexpr int CHUNK = 8192;                 // edges per hist/scatter block

// ---- A: per-chunk histogram of dst>>NB_SHIFT (LDS atomics only) --------
__global__ __launch_bounds__(TPB) void k_bhist(const int* __restrict__ dst, int E, int nbuck,
                                               int* __restrict__ blockHist) {
    extern __shared__ int sh[];  // nbuck ints
    for (int i = threadIdx.x; i < nbuck; i += TPB) sh[i] = 0;
    __syncthreads();
    int base = blockIdx.x * CHUNK;
    int end = min(base + CHUNK, E);
    for (int e = base + threadIdx.x; e < end; e += TPB)
        atomicAdd(&sh[dst[e] >> NB_SHIFT], 1);
    __syncthreads();
    int* out = blockHist + (size_t)blockIdx.x * nbuck;
    for (int i = threadIdx.x; i < nbuck; i += TPB) out[i] = sh[i];
}

// ---- B: column scan of blockHist (in place -> per-chunk offsets) + bucket bases
__global__ __launch_bounds__(512) void k_boffsets(int* __restrict__ blockHist, int nchunks,
                                                  int nbuck, int* __restrict__ bucketBase) {
    __shared__ int tot[512];
    int b = threadIdx.x;
    int run = 0;
    if (b < nbuck) {
        for (int c = 0; c < nchunks; ++c) {
            size_t idx = (size_t)c * nbuck + b;   // coalesced across threads
            int v = blockHist[idx];
            blockHist[idx] = run;                 // exclusive within-bucket prefix
            run += v;
        }
    }
    tot[b] = (b < nbuck) ? run : 0;
    __syncthreads();
    // inclusive Hillis-Steele scan over 512
    for (int s = 1; s < 512; s <<= 1) {
        int add = (b >= s) ? tot[b - s] : 0;
        __syncthreads();
        tot[b] += add;
        __syncthreads();
    }
    if (b < nbuck) {
        bucketBase[b] = tot[b] - run;             // exclusive
        if (b == nbuck - 1) bucketBase[nbuck] = tot[b];
    }
}

// ---- C: scatter packed (dstLocal<<17 | src) into bucket-major order ----
__global__ __launch_bounds__(TPB) void k_bscatter(const int* __restrict__ src,
                                                  const int* __restrict__ dst, int E, int nbuck,
                                                  const int* __restrict__ blockHist,
                                                  const int* __restrict__ bucketBase,
                                                  unsigned* __restrict__ packed) {
    extern __shared__ int cur[];  // nbuck cursors
    const int* off = blockHist + (size_t)blockIdx.x * nbuck;
    for (int i = threadIdx.x; i < nbuck; i += TPB) cur[i] = off[i] + bucketBase[i];
    __syncthreads();
    int base = blockIdx.x * CHUNK;
    int end = min(base + CHUNK, E);
    for (int e = base + threadIdx.x; e < end; e += TPB) {
        int s = src[e];
        int d = dst[e];
        int b = d >> NB_SHIFT;
        int pos = atomicAdd(&cur[b], 1);          // LDS atomic
        packed[pos] = ((unsigned)(d & (BUCK_NODES - 1)) << 17) | (unsigned)s;
    }
}

// ---- D: per-node degree -> dinv (bucket-local LDS counts) --------------
__global__ __launch_bounds__(TPB) void k_dinv(const unsigned* __restrict__ packed,
                                              const int* __restrict__ bucketBase, int n,
                                              float* __restrict__ dinv) {
    __shared__ int cnt[BUCK_NODES];
    cnt[threadIdx.x] = 0;
    __syncthreads();
    int e0 = bucketBase[blockIdx.x], e1 = bucketBase[blockIdx.x + 1];
    for (int e = e0 + threadIdx.x; e < e1; e += TPB)
        atomicAdd(&cnt[packed[e] >> 17], 1);
    __syncthreads();
    int node = blockIdx.x * BUCK_NODES + threadIdx.x;
    if (node < n) dinv[node] = rsqrtf(1.0f + (float)cnt[threadIdx.x]);
}

// ---- GEMM: out[i][f] = (sum_k A[i][k] * W[k][f]) * dinv[i] -------------
__global__ __launch_bounds__(256) void k_gemm64(const float* __restrict__ A, const float* __restrict__ W,
                                                const float* __restrict__ dinv, float* __restrict__ out,
                                                int n) {
    const int lane = threadIdx.x & 63;
    const int wave = threadIdx.x >> 6;
    float wcol[64];
#pragma unroll
    for (int k = 0; k < 64; ++k) wcol[k] = W[k * 64 + lane];
    int base = blockIdx.x * 64;
    for (int r = wave; r < 64; r += 4) {
        int row = base + r;
        if (row >= n) break;
        float a = A[(size_t)row * 64 + lane];
        float acc = 0.0f;
#pragma unroll
        for (int k = 0; k < 64; ++k) {
            float ak = __uint_as_float(__builtin_amdgcn_readlane(__float_as_uint(a), k));
            acc = fmaf(ak, wcol[k], acc);
        }
        out[(size_t)row * 64 + lane] = acc * dinv[row];
    }
}

// ---- Aggregate per bucket: LDS accumulator, fused bias+ReLU (+head) ----
template <bool LAST>
__global__ __launch_bounds__(512) void k_agg(const float* __restrict__ g,
                                             const unsigned* __restrict__ packed,
                                             const int* __restrict__ bucketBase,
                                             const float* __restrict__ dinv,
                                             const float* __restrict__ bias,
                                             const float* __restrict__ Wo,
                                             const float* __restrict__ bo,
                                             float* __restrict__ out, int n) {
    extern __shared__ float acc[];                 // BUCK_NODES*64 floats = 64 KB
    float4* a4 = (float4*)acc;
    for (int i = threadIdx.x; i < BUCK_NODES * 16; i += 512) a4[i] = float4{0, 0, 0, 0};
    __syncthreads();
    const int wave = threadIdx.x >> 6;
    const int lane = threadIdx.x & 63;
    const int e0 = bucketBase[blockIdx.x], e1 = bucketBase[blockIdx.x + 1];
    const int cnt = e1 - e0;
    // 8 waves x 4 edges in flight each
    for (int eb = wave * 4; eb < cnt; eb += 32) {
        int m = min(4, cnt - eb);
        unsigned pk[4];
        float v[4];
#pragma unroll
        for (int k = 0; k < 4; ++k)
            if (k < m) {
                pk[k] = packed[e0 + eb + k];
                v[k] = g[(size_t)(pk[k] & 0x1FFFFu) * 64 + lane];
            }
#pragma unroll
        for (int k = 0; k < 4; ++k)
            if (k < m) atomicAdd(&acc[(pk[k] >> 17) * 64 + lane], v[k]);
    }
    __syncthreads();
    // epilogue: 256 nodes / 8 waves; self-loop + bias + relu (+ head GEMV)
    for (int nl = wave; nl < BUCK_NODES; nl += 8) {
        int node = blockIdx.x * BUCK_NODES + nl;
        if (node >= n) break;
        float a = acc[nl * 64 + lane] + g[(size_t)node * 64 + lane];
        float v = fmaxf(fmaf(dinv[node], a, bias[lane]), 0.0f);
        if constexpr (LAST) {
            float p = v * Wo[lane];
#pragma unroll
            for (int s = 32; s > 0; s >>= 1) p += __shfl_xor(p, s, 64);
            if (lane == 0) out[node] = p + bo[0];
        } else {
            out[(size_t)node * 64 + lane] = v;
        }
    }
}

extern "C" void kernel_launch(void* const* d_in, const int* in_sizes, int n_in,
                              void* d_out, int out_size, void* d_ws, size_t ws_size,
                              hipStream_t stream) {
    const float* x  = (const float*)d_in[0];
    const int*   ei = (const int*)d_in[1];
    const float* W1 = (const float*)d_in[2];
    const float* b1 = (const float*)d_in[3];
    const float* W2 = (const float*)d_in[4];
    const float* b2 = (const float*)d_in[5];
    const float* Wo = (const float*)d_in[6];
    const float* bo = (const float*)d_in[7];
    float* out = (float*)d_out;

    const int n = in_sizes[0] / 64;
    const int E = in_sizes[1] / 2;
    const int* src = ei;
    const int* dst = ei + E;

    const int nbuck = (n + BUCK_NODES - 1) >> NB_SHIFT;      // 391
    const int nchunks = (E + CHUNK - 1) / CHUNK;             // 153

    char* ws = (char*)d_ws;
    size_t off = 0;
    auto alloc = [&](size_t bytes) -> void* {
        void* p = ws + off;
        off += (bytes + 255) & ~(size_t)255;
        return p;
    };
    float*    dinv       = (float*)alloc((size_t)n * 4);
    int*      bucketBase = (int*)alloc((size_t)(nbuck + 1) * 4);
    int*      blockHist  = (int*)alloc((size_t)nchunks * nbuck * 4);
    unsigned* packed     = (unsigned*)alloc((size_t)E * 4);
    float*    bufG       = (float*)alloc((size_t)n * 64 * 4);
    float*    bufH       = (float*)alloc((size_t)n * 64 * 4);

    const size_t histLds = (size_t)nbuck * 4;
    const size_t accLds  = (size_t)BUCK_NODES * 64 * 4;      // 64 KB

    // ---- bucketed counting sort of edges by dst (dense writes) ----
    k_bhist<<<nchunks, TPB, histLds, stream>>>(dst, E, nbuck, blockHist);
    k_boffsets<<<1, 512, 0, stream>>>(blockHist, nchunks, nbuck, bucketBase);
    k_bscatter<<<nchunks, TPB, histLds, stream>>>(src, dst, E, nbuck, blockHist, bucketBase, packed);
    k_dinv<<<nbuck, TPB, 0, stream>>>(packed, bucketBase, n, dinv);

    const int gemmGrid = (n + 63) / 64;

    // ---- layer 1 ----
    k_gemm64<<<gemmGrid, TPB, 0, stream>>>(x, W1, dinv, bufG, n);
    k_agg<false><<<nbuck, 512, accLds, stream>>>(bufG, packed, bucketBase, dinv, b1,
                                                 nullptr, nullptr, bufH, n);
    // ---- layer 2 (head fused into epilogue) ----
    k_gemm64<<<gemmGrid, TPB, 0, stream>>>(bufH, W2, dinv, bufG, n);
    k_agg<true><<<nbuck, 512, accLds, stream>>>(bufG, packed, bucketBase, dinv, b2,
                                                Wo, bo, out, n);
}

// Round 4
// 266.757 us; speedup vs baseline: 4.7027x; 4.7027x over previous
//
#include <hip/hip_runtime.h>

// GCN 2-layer + linear head on MI355X.
// R3: R2's LDS-atomic aggregation was 572us (80M ds-atomics, 29% occupancy).
// Now: bucketed counting sort -> full dst-sorted CSR (per-bucket LDS sort,
// dense writes), then one-wave-per-node register aggregation (no atomics),
// head GEMV fused into layer-2 epilogue.

constexpr int TPB = 256;
constexpr int NB_SHIFT = 8;                 // 256 nodes per bucket
constexpr int BUCK_NODES = 1 << NB_SHIFT;
constexpr int CHUNK = 8192;                 // edges per hist/scatter block

// ---- A: per-chunk histogram of dst>>NB_SHIFT (LDS atomics only) --------
__global__ __launch_bounds__(TPB) void k_bhist(const int* __restrict__ dst, int E, int nbuck,
                                               int* __restrict__ blockHist) {
    extern __shared__ int sh[];  // nbuck ints
    for (int i = threadIdx.x; i < nbuck; i += TPB) sh[i] = 0;
    __syncthreads();
    int base = blockIdx.x * CHUNK;
    int end = min(base + CHUNK, E);
    for (int e = base + threadIdx.x; e < end; e += TPB)
        atomicAdd(&sh[dst[e] >> NB_SHIFT], 1);
    __syncthreads();
    int* out = blockHist + (size_t)blockIdx.x * nbuck;
    for (int i = threadIdx.x; i < nbuck; i += TPB) out[i] = sh[i];
}

// ---- B: column scan of blockHist (in place -> per-chunk offsets) + bucket bases
__global__ __launch_bounds__(512) void k_boffsets(int* __restrict__ blockHist, int nchunks,
                                                  int nbuck, int* __restrict__ bucketBase) {
    __shared__ int tot[512];
    int b = threadIdx.x;
    int run = 0;
    if (b < nbuck) {
        for (int c = 0; c < nchunks; ++c) {
            size_t idx = (size_t)c * nbuck + b;   // coalesced across threads
            int v = blockHist[idx];
            blockHist[idx] = run;                 // exclusive within-bucket prefix
            run += v;
        }
    }
    tot[b] = (b < nbuck) ? run : 0;
    __syncthreads();
    for (int s = 1; s < 512; s <<= 1) {
        int add = (b >= s) ? tot[b - s] : 0;
        __syncthreads();
        tot[b] += add;
        __syncthreads();
    }
    if (b < nbuck) {
        bucketBase[b] = tot[b] - run;             // exclusive
        if (b == nbuck - 1) bucketBase[nbuck] = tot[b];
    }
}

// ---- C: scatter packed (dstLocal<<17 | src) into bucket-major order ----
__global__ __launch_bounds__(TPB) void k_bscatter(const int* __restrict__ src,
                                                  const int* __restrict__ dst, int E, int nbuck,
                                                  const int* __restrict__ blockHist,
                                                  const int* __restrict__ bucketBase,
                                                  unsigned* __restrict__ packed) {
    extern __shared__ int cur[];  // nbuck cursors
    const int* off = blockHist + (size_t)blockIdx.x * nbuck;
    for (int i = threadIdx.x; i < nbuck; i += TPB) cur[i] = off[i] + bucketBase[i];
    __syncthreads();
    int base = blockIdx.x * CHUNK;
    int end = min(base + CHUNK, E);
    for (int e = base + threadIdx.x; e < end; e += TPB) {
        int s = src[e];
        int d = dst[e];
        int b = d >> NB_SHIFT;
        int pos = atomicAdd(&cur[b], 1);          // LDS atomic
        packed[pos] = ((unsigned)(d & (BUCK_NODES - 1)) << 17) | (unsigned)s;
    }
}

// ---- D: per-bucket counting sort by dstLocal -> CSR + rowptr + dinv ----
__global__ __launch_bounds__(BUCK_NODES) void k_csr(const unsigned* __restrict__ packed,
                                                    const int* __restrict__ bucketBase, int n, int E,
                                                    int* __restrict__ csr, int* __restrict__ rowptr,
                                                    float* __restrict__ dinv) {
    __shared__ int cnt[BUCK_NODES];
    __shared__ int scn[BUCK_NODES];
    __shared__ int cur[BUCK_NODES];
    const int tid = threadIdx.x;
    const int e0 = bucketBase[blockIdx.x], e1 = bucketBase[blockIdx.x + 1];
    cnt[tid] = 0;
    __syncthreads();
    for (int e = e0 + tid; e < e1; e += BUCK_NODES)
        atomicAdd(&cnt[packed[e] >> 17], 1);
    __syncthreads();
    int v = cnt[tid];
    scn[tid] = v;
    __syncthreads();
    for (int s = 1; s < BUCK_NODES; s <<= 1) {   // inclusive Hillis-Steele
        int add = (tid >= s) ? scn[tid - s] : 0;
        __syncthreads();
        scn[tid] += add;
        __syncthreads();
    }
    int exc = e0 + scn[tid] - v;
    cur[tid] = exc;
    int node = blockIdx.x * BUCK_NODES + tid;
    if (node < n) {
        rowptr[node] = exc;
        dinv[node] = rsqrtf(1.0f + (float)v);
    }
    if (blockIdx.x == gridDim.x - 1 && tid == BUCK_NODES - 1) rowptr[n] = E;
    __syncthreads();
    for (int e = e0 + tid; e < e1; e += BUCK_NODES) {
        unsigned p = packed[e];
        int pos = atomicAdd(&cur[p >> 17], 1);   // LDS cursor
        csr[pos] = (int)(p & 0x1FFFFu);          // dense ~13KB window, L2-hot
    }
}

// ---- GEMM: out[i][f] = (sum_k A[i][k] * W[k][f]) * dinv[i] -------------
__global__ __launch_bounds__(256) void k_gemm64(const float* __restrict__ A, const float* __restrict__ W,
                                                const float* __restrict__ dinv, float* __restrict__ out,
                                                int n) {
    const int lane = threadIdx.x & 63;
    const int wave = threadIdx.x >> 6;
    float wcol[64];
#pragma unroll
    for (int k = 0; k < 64; ++k) wcol[k] = W[k * 64 + lane];
    int base = blockIdx.x * 64;
    for (int r = wave; r < 64; r += 4) {
        int row = base + r;
        if (row >= n) break;
        float a = A[(size_t)row * 64 + lane];
        float acc = 0.0f;
#pragma unroll
        for (int k = 0; k < 64; ++k) {
            float ak = __uint_as_float(__builtin_amdgcn_readlane(__float_as_uint(a), k));
            acc = fmaf(ak, wcol[k], acc);
        }
        out[(size_t)row * 64 + lane] = acc * dinv[row];
    }
}

// ---- Aggregate: one wave per node, register accumulator, no atomics ----
// out[i][f] = relu(dinv[i]*(g[i][f] + sum_nb g[s][f]) + b[f]); LAST fuses head.
template <bool LAST>
__global__ __launch_bounds__(256) void k_aggregate(const float* __restrict__ g,
                                                   const int* __restrict__ rowptr,
                                                   const int* __restrict__ csr,
                                                   const float* __restrict__ dinv,
                                                   const float* __restrict__ bias,
                                                   const float* __restrict__ Wo,
                                                   const float* __restrict__ bo,
                                                   float* __restrict__ out, int n) {
    int t = blockIdx.x * blockDim.x + threadIdx.x;
    int node = t >> 6;
    int lane = t & 63;
    if (node >= n) return;
    int e = rowptr[node];
    int e1 = rowptr[node + 1];
    float acc = g[(size_t)node * 64 + lane];  // self-loop term
    for (; e + 4 <= e1; e += 4) {
        int i0 = csr[e], i1 = csr[e + 1], i2 = csr[e + 2], i3 = csr[e + 3];
        float a0 = g[(size_t)i0 * 64 + lane];
        float a1 = g[(size_t)i1 * 64 + lane];
        float a2 = g[(size_t)i2 * 64 + lane];
        float a3 = g[(size_t)i3 * 64 + lane];
        acc += (a0 + a1) + (a2 + a3);
    }
    for (; e < e1; ++e) acc += g[(size_t)csr[e] * 64 + lane];
    float vv = fmaxf(fmaf(dinv[node], acc, bias[lane]), 0.0f);
    if constexpr (LAST) {
        float p = vv * Wo[lane];
#pragma unroll
        for (int s = 32; s > 0; s >>= 1) p += __shfl_xor(p, s, 64);
        if (lane == 0) out[node] = p + bo[0];
    } else {
        out[(size_t)node * 64 + lane] = vv;
    }
}

extern "C" void kernel_launch(void* const* d_in, const int* in_sizes, int n_in,
                              void* d_out, int out_size, void* d_ws, size_t ws_size,
                              hipStream_t stream) {
    const float* x  = (const float*)d_in[0];
    const int*   ei = (const int*)d_in[1];
    const float* W1 = (const float*)d_in[2];
    const float* b1 = (const float*)d_in[3];
    const float* W2 = (const float*)d_in[4];
    const float* b2 = (const float*)d_in[5];
    const float* Wo = (const float*)d_in[6];
    const float* bo = (const float*)d_in[7];
    float* out = (float*)d_out;

    const int n = in_sizes[0] / 64;
    const int E = in_sizes[1] / 2;
    const int* src = ei;
    const int* dst = ei + E;

    const int nbuck = (n + BUCK_NODES - 1) >> NB_SHIFT;      // 391
    const int nchunks = (E + CHUNK - 1) / CHUNK;             // 153

    char* ws = (char*)d_ws;
    size_t off = 0;
    auto alloc = [&](size_t bytes) -> void* {
        void* p = ws + off;
        off += (bytes + 255) & ~(size_t)255;
        return p;
    };
    float*    dinv       = (float*)alloc((size_t)n * 4);
    int*      bucketBase = (int*)alloc((size_t)(nbuck + 1) * 4);
    int*      blockHist  = (int*)alloc((size_t)nchunks * nbuck * 4);
    unsigned* packed     = (unsigned*)alloc((size_t)E * 4);
    int*      csr        = (int*)alloc((size_t)E * 4);
    int*      rowptr     = (int*)alloc((size_t)(n + 1) * 4);
    float*    bufG       = (float*)alloc((size_t)n * 64 * 4);
    float*    bufH       = (float*)alloc((size_t)n * 64 * 4);

    const size_t histLds = (size_t)nbuck * 4;

    // ---- bucketed counting sort -> dst-sorted CSR + rowptr + dinv ----
    k_bhist<<<nchunks, TPB, histLds, stream>>>(dst, E, nbuck, blockHist);
    k_boffsets<<<1, 512, 0, stream>>>(blockHist, nchunks, nbuck, bucketBase);
    k_bscatter<<<nchunks, TPB, histLds, stream>>>(src, dst, E, nbuck, blockHist, bucketBase, packed);
    k_csr<<<nbuck, BUCK_NODES, 0, stream>>>(packed, bucketBase, n, E, csr, rowptr, dinv);

    const int gemmGrid = (n + 63) / 64;
    const int nodeGrid = (n * 64 + TPB - 1) / TPB;

    // ---- layer 1 ----
    k_gemm64<<<gemmGrid, TPB, 0, stream>>>(x, W1, dinv, bufG, n);
    k_aggregate<false><<<nodeGrid, TPB, 0, stream>>>(bufG, rowptr, csr, dinv, b1,
                                                     nullptr, nullptr, bufH, n);
    // ---- layer 2 (head fused into epilogue) ----
    k_gemm64<<<gemmGrid, TPB, 0, stream>>>(bufH, W2, dinv, bufG, n);
    k_aggregate<true><<<nodeGrid, TPB, 0, stream>>>(bufG, rowptr, csr, dinv, b2,
                                                    Wo, bo, out, n);
}